// Round 1
// baseline (10390.907 us; speedup 1.0000x reference)
//
#include <hip/hip_runtime.h>

typedef __attribute__((ext_vector_type(4))) float f32x4;
typedef __attribute__((ext_vector_type(8))) short s16x8;
typedef unsigned long long u64;

__device__ __forceinline__ unsigned short f2bf(float f) {
  union { float f; unsigned u; } v; v.f = f;
  unsigned r = v.u + 0x7fffu + ((v.u >> 16) & 1u);
  return (unsigned short)(r >> 16);
}

// ---------------- prep kernels ----------------

// Wbig[c] (1024x512) = [hcomb_W[c]; W_hh[c] @ hcomb_W[c]] as bf16
// bbig[c] (1024)     = [hcomb_b[c]; W_hh[c] @ hcomb_b[c] + b_hh[c]]
__global__ void prep_wbig(const float* __restrict__ hcomb_W, const float* __restrict__ hcomb_b,
                          const float* __restrict__ W_hh, const float* __restrict__ b_hh,
                          unsigned short* __restrict__ Wbig, float* __restrict__ bbig) {
  __shared__ float red[256];
  const int c = blockIdx.x, g = blockIdx.y, t = threadIdx.x;
  const float* hW = hcomb_W + (size_t)c * 256 * 512;
  unsigned short* orow = Wbig + ((size_t)c * 1024 + g) * 512;
  if (g < 256) {
    orow[t]       = f2bf(hW[(size_t)g * 512 + t]);
    orow[t + 256] = f2bf(hW[(size_t)g * 512 + t + 256]);
    if (t == 0) bbig[c * 1024 + g] = hcomb_b[c * 256 + g];
    return;
  }
  const int gp = g - 256;
  const float* wrow = W_hh + ((size_t)c * 768 + gp) * 256;
  float a0 = 0.f, a1 = 0.f;
  for (int h = 0; h < 256; h++) {
    float w = wrow[h];
    a0 += w * hW[(size_t)h * 512 + t];
    a1 += w * hW[(size_t)h * 512 + t + 256];
  }
  orow[t] = f2bf(a0); orow[t + 256] = f2bf(a1);
  red[t] = wrow[t] * hcomb_b[c * 256 + t];
  __syncthreads();
  for (int s = 128; s > 0; s >>= 1) { if (t < s) red[t] += red[t + s]; __syncthreads(); }
  if (t == 0) bbig[c * 1024 + g] = red[0] + b_hh[c * 768 + gp];
}

// U_{l,a}[c][v][f] = sum_e emb[c][v][e] * xcomb_W[c][f][side*256 + e]
__global__ void prep_u(const float* __restrict__ emb, const float* __restrict__ xcomb_W,
                       float* __restrict__ Ul, float* __restrict__ Ua) {
  __shared__ float er[256];
  const int c = blockIdx.x, v = blockIdx.y, side = blockIdx.z, f = threadIdx.x;
  er[f] = emb[((size_t)c * 257 + v) * 256 + f];
  __syncthreads();
  const float* wrow = xcomb_W + ((size_t)c * 256 + f) * 512 + side * 256;
  float a = 0.f;
  for (int e = 0; e < 256; e++) a += er[e] * wrow[e];
  (side ? Ua : Ul)[((size_t)c * 257 + v) * 256 + f] = a;
}

// T_{l,a}[c][v][g] = sum_f W_ih[c][g][f] * U[c][v][f]
__global__ void prep_t(const float* __restrict__ W_ih, const float* __restrict__ Ul,
                       const float* __restrict__ Ua, float* __restrict__ Tl, float* __restrict__ Ta) {
  __shared__ float ur[256];
  const int c = blockIdx.x, v = blockIdx.y, side = blockIdx.z, g = threadIdx.x; // block 768
  if (g < 256) ur[g] = (side ? Ua : Ul)[((size_t)c * 257 + v) * 256 + g];
  __syncthreads();
  const float* wrow = W_ih + ((size_t)c * 768 + g) * 258;
  float a = 0.f;
  for (int f = 0; f < 256; f++) a += ur[f] * wrow[f];
  (side ? Ta : Tl)[((size_t)c * 257 + v) * 768 + g] = a;
}

// bgx[c][g] = b_ih[c][g] + sum_f W_ih[c][g][f] * xcomb_b[c][f]
__global__ void prep_bgx(const float* __restrict__ W_ih, const float* __restrict__ xcomb_b,
                         const float* __restrict__ b_ih, float* __restrict__ bgx) {
  __shared__ float xb[256];
  const int c = blockIdx.x, g = threadIdx.x; // block 768
  if (g < 256) xb[g] = xcomb_b[c * 256 + g];
  __syncthreads();
  const float* wrow = W_ih + ((size_t)c * 768 + g) * 258;
  float a = b_ih[c * 768 + g];
  for (int f = 0; f < 256; f++) a += xb[f] * wrow[f];
  bgx[c * 768 + g] = a;
}

// TG[v][u]  = emb[0][v] . green_W[u][256:512]
// TB0[v][u] = emb[0][v] . blue_W[u][256:512]
// TB1[v][u] = emb[1][v] . blue_W[u][512:768]
__global__ void prep_tgb(const float* __restrict__ emb, const float* __restrict__ green_W,
                         const float* __restrict__ blue_W,
                         float* __restrict__ TG, float* __restrict__ TB0, float* __restrict__ TB1) {
  __shared__ float er[256];
  const int v = blockIdx.x, which = blockIdx.y, u = threadIdx.x; // block 320
  const int ch = (which == 2) ? 1 : 0;
  if (u < 256) er[u] = emb[((size_t)ch * 257 + v) * 256 + u];
  __syncthreads();
  if (u >= 257) return;
  const float* W; int pitch, off; float* T;
  if (which == 0)      { W = green_W; pitch = 512; off = 256; T = TG;  }
  else if (which == 1) { W = blue_W;  pitch = 768; off = 256; T = TB0; }
  else                 { W = blue_W;  pitch = 768; off = 512; T = TB1; }
  const float* wrow = W + (size_t)u * pitch + off;
  float a = 0.f;
  for (int e = 0; e < 256; e++) a += er[e] * wrow[e];
  T[(size_t)v * 257 + u] = a;
}

// W3[c] (272x256) bf16 = h-part of {red_W, green_W, blue_W}; rows >=257 zero
__global__ void prep_w3(const float* __restrict__ red_W, const float* __restrict__ green_W,
                        const float* __restrict__ blue_W, unsigned short* __restrict__ W3) {
  const int c = blockIdx.x, v = blockIdx.y, t = threadIdx.x; // block 256
  float val = 0.f;
  if (v < 257) {
    if (c == 0)      val = red_W[(size_t)v * 256 + t];
    else if (c == 1) val = green_W[(size_t)v * 512 + t];
    else             val = blue_W[(size_t)v * 768 + t];
  }
  W3[((size_t)c * 272 + v) * 256 + t] = f2bf(val);
}

// NEW: materialize per-cell gate-x preactivations (index-static, BW-bound, off critical path)
// pregx[cell][gate(3)][b(128)][j(256)]; gate r,z include their gh biases (folded into MFMA C-init);
// gate n excludes bn (bn is inside the r-multiplied term).
__global__ void prep_gx(const int* __restrict__ x,
                        const float* __restrict__ Tl, const float* __restrict__ Ta,
                        const float* __restrict__ bgx, const float* __restrict__ bbig,
                        const float* __restrict__ W_ih, float* __restrict__ pregx) {
  __shared__ float base[768];
  __shared__ int ix0[128], ix1[128];
  const int r = blockIdx.x, k = blockIdx.y, c = blockIdx.z, tid = threadIdx.x; // block 256
  for (int g = tid; g < 768; g += 256) {
    float v = bgx[c * 768 + g]
            + (float)r * W_ih[((size_t)c * 768 + g) * 258 + 256]
            + (float)k * W_ih[((size_t)c * 768 + g) * 258 + 257];
    if (g < 512) v += bbig[c * 1024 + 256 + g];   // br / bz folded in
    base[g] = v;
  }
  if (tid < 128) {
    ix0[tid] = x[((tid * 3 + c) * 32 + (r + 1)) * 32 + k];       // left index
    ix1[tid] = x[((tid * 3 + c) * 32 + r) * 32 + (k + 1)];       // above index
  }
  __syncthreads();
  const size_t cell = ((size_t)(r * 31 + k)) * 3 + c;
  float* outp = pregx + cell * 3 * 128 * 256;
  const float* Tlc = Tl + (size_t)c * 257 * 768;
  const float* Tac = Ta + (size_t)c * 257 * 768;
  #pragma unroll 2
  for (int b = 0; b < 128; ++b) {
    const float* tl = Tlc + (size_t)ix0[b] * 768;
    const float* ta = Tac + (size_t)ix1[b] * 768;
    #pragma unroll
    for (int q = 0; q < 3; ++q) {
      const int g = q * 256 + tid;
      outp[((size_t)q * 128 + b) * 256 + tid] = tl[g] + ta[g] + base[g];
    }
  }
}

__global__ void zero_flags(int* __restrict__ f, int n) {
  int i = blockIdx.x * 256 + threadIdx.x;
  if (i < n) f[i] = 0;
}

// ---------------- persistent wavefront kernel ----------------
// Replaces 124 per-level launches. Per-(row,level) flags; rows pipeline with slack
// instead of global-barrier lockstep.
// sflag[L][r]: 4 role blocks of row r post (release/agent) after writing h at level L.
// eflag[Le][r]: epi block r posts after it has finished READING hbuf for its iter Le.
// step(r,L) waits: sflag[L-1][r] (pl, t>=1), sflag[L-1][r-1] (above, r>=1),
//                  sflag[L-2][r+1] + eflag[L-2][r] (anti-dep: slot (r,c) reuse, t>=3).

__device__ __forceinline__ void spinwait(int* f, int target) {
  while (__hip_atomic_load(f, __ATOMIC_RELAXED, __HIP_MEMORY_SCOPE_AGENT) < target)
    __builtin_amdgcn_s_sleep(2);
}

__global__ __launch_bounds__(256, 2)
void persist_kernel(const int* __restrict__ x, float* __restrict__ hbuf,
                    const unsigned short* __restrict__ Wbig, const float* __restrict__ bbig,
                    const float* __restrict__ pregx,
                    const unsigned short* __restrict__ W3,
                    const float* __restrict__ TG, const float* __restrict__ TB0,
                    const float* __restrict__ TB1,
                    const float* __restrict__ red_b, const float* __restrict__ green_b,
                    const float* __restrict__ blue_b,
                    float* __restrict__ out, int* __restrict__ flags)
{
  __shared__ unsigned short Abuf[128 * 136];
  __shared__ int idx0[128], idx1[128];

  // XCD swizzle: all 5 blocks of row r share (id & 7) -> same XCD under %8 round-robin.
  const int id = blockIdx.x;
  const int rlo = id & 7, slot = id >> 3;
  const int rhi = slot / 5, role = slot - 5 * rhi;
  const int r = rlo + 8 * rhi;
  if (r > 30) return;

  int* sflag = flags;              // [124][31]
  int* eflag = flags + 124 * 31;   // [124][31]

  const int tid = threadIdx.x;
  const int lane = tid & 63, wv = tid >> 6;
  const int quad = lane >> 4, l16 = lane & 15;

  if (role < 4) {
    // ---------------- recurrent step: row r, levels L = r .. r+92 ----------------
    const int jcol = role * 64 + wv * 16;
    const int j = jcol + l16;

    for (int L = r; L <= r + 92; ++L) {
      const int t = L - r;
      const int k = t / 3, c = t - 3 * k;
      const size_t cell = ((size_t)(r * 31 + k)) * 3 + c;
      const float* pg = pregx + cell * 3 * 128 * 256;

      // acc C-init from pregx (independent of flags -> issued before the wait)
      f32x4 acc[8][4];
      const float bh  = bbig[c * 1024 + j];
      const float bn3 = bbig[c * 1024 + 768 + j];
      #pragma unroll
      for (int mt = 0; mt < 8; ++mt)
        #pragma unroll
        for (int i = 0; i < 4; ++i) {
          const int b = mt * 16 + quad * 4 + i;
          acc[mt][0][i] = bh;                                   // h bias
          acc[mt][1][i] = pg[(size_t)b * 256 + j];              // gxr + br
          acc[mt][2][i] = pg[(size_t)(128 + b) * 256 + j];      // gxz + bz
          acc[mt][3][i] = bn3;                                  // bn (inside r* term)
        }

      // wait for producers / consumers of the hbuf slots we touch
      if (tid == 0) {
        if (t >= 1) spinwait(&sflag[(L - 1) * 31 + r], 4);
        if (r >= 1) spinwait(&sflag[(L - 1) * 31 + (r - 1)], 4);
        if (t >= 3) {
          if (r < 30) spinwait(&sflag[(L - 2) * 31 + (r + 1)], 4);
          spinwait(&eflag[(L - 2) * 31 + r], 1);
        }
      }
      __syncthreads();
      __builtin_amdgcn_fence(__ATOMIC_ACQUIRE, "agent");  // invalidate stale L1/L2 lines

      const bool pl_zero = (t == 0);
      const bool a_zero  = (r == 0);
      const float* plp = hbuf + ((size_t)(r * 3 + (c == 0 ? 2 : c - 1)) * 128) * 256;
      const float* ap  = (r > 0) ? hbuf + ((size_t)((r - 1) * 3 + c) * 128) * 256 : hbuf;
      const unsigned short* Wb = Wbig + (size_t)c * 1024 * 512;

      for (int kc = 0; kc < 4; ++kc) {
        const bool from_pl = (kc < 2);
        const float* src = from_pl ? plp : ap;
        const bool zero = from_pl ? pl_zero : a_zero;
        const int colbase = from_pl ? kc * 128 : (kc - 2) * 128;
        __syncthreads();
        #pragma unroll 8
        for (int it = 0; it < 16; ++it) {
          const int li = it * 256 + tid;
          const int row = li >> 5;
          const int col = (li & 31) * 4;
          unsigned short o0 = 0, o1 = 0, o2 = 0, o3 = 0;
          if (!zero) {
            const float4 v = *(const float4*)(src + (size_t)row * 256 + colbase + col);
            o0 = f2bf(v.x); o1 = f2bf(v.y); o2 = f2bf(v.z); o3 = f2bf(v.w);
          }
          unsigned short* d = &Abuf[row * 136 + col];
          d[0] = o0; d[1] = o1; d[2] = o2; d[3] = o3;
        }
        __syncthreads();
        #pragma unroll
        for (int ks = 0; ks < 4; ++ks) {
          const int kofs = ks * 32 + quad * 8;
          s16x8 bf[4];
          #pragma unroll
          for (int g = 0; g < 4; ++g)
            bf[g] = *(const s16x8*)(Wb + (size_t)(g * 256 + jcol + l16) * 512 + kc * 128 + kofs);
          #pragma unroll
          for (int mt = 0; mt < 8; ++mt) {
            const s16x8 af = *(const s16x8*)&Abuf[(mt * 16 + l16) * 136 + kofs];
            #pragma unroll
            for (int g = 0; g < 4; ++g)
              acc[mt][g] = __builtin_amdgcn_mfma_f32_16x16x32_bf16(af, bf[g], acc[mt][g], 0, 0, 0);
          }
        }
      }

      // GRU epilogue: acc[0]=h, acc[1]=gxr+ghr, acc[2]=gxz+ghz, acc[3]=ghn
      const float* pgn = pg + (size_t)2 * 128 * 256;
      float* hout = hbuf + ((size_t)(r * 3 + c) * 128) * 256;
      #pragma unroll
      for (int mt = 0; mt < 8; ++mt)
        #pragma unroll
        for (int i = 0; i < 4; ++i) {
          const int b = mt * 16 + quad * 4 + i;
          const float gxn = pgn[(size_t)b * 256 + j];
          const float h  = acc[mt][0][i];
          const float rg = __fdividef(1.f, 1.f + __expf(-acc[mt][1][i]));
          const float zg = __fdividef(1.f, 1.f + __expf(-acc[mt][2][i]));
          const float ng = 1.f - __fdividef(2.f, __expf(2.f * (gxn + rg * acc[mt][3][i])) + 1.f);
          hout[(size_t)b * 256 + j] = (1.f - zg) * ng + zg * h;
        }

      __syncthreads();   // drain all threads' h stores (barrier implies vmcnt(0))
      if (tid == 0)
        __hip_atomic_fetch_add(&sflag[L * 31 + r], 1, __ATOMIC_RELEASE, __HIP_MEMORY_SCOPE_AGENT);
    }
  } else {
    // ---------------- logits epilogue: row r, iters Le = r+1 .. r+93 (cell level Le-1) ----------------
    for (int Le = r + 1; Le <= r + 93; ++Le) {
      const int t = Le - 1 - r;
      const int k = t / 3, c = t - 3 * k;

      if (tid == 0) spinwait(&sflag[(Le - 1) * 31 + r], 4);
      __syncthreads();
      __builtin_amdgcn_fence(__ATOMIC_ACQUIRE, "agent");

      if (tid < 128) {
        idx0[tid] = x[((tid * 3 + 0) * 32 + (r + 1)) * 32 + (k + 1)];  // target ch0
        idx1[tid] = x[((tid * 3 + 1) * 32 + (r + 1)) * 32 + (k + 1)];  // target ch1
      }

      const float* hsrc = hbuf + ((size_t)(r * 3 + c) * 128) * 256;
      const unsigned short* W3c = W3 + (size_t)c * 272 * 256;

      f32x4 acc[2][17];
      #pragma unroll
      for (int m2 = 0; m2 < 2; ++m2)
        #pragma unroll
        for (int nt = 0; nt < 17; ++nt)
          #pragma unroll
          for (int e = 0; e < 4; ++e) acc[m2][nt][e] = 0.f;

      for (int kc = 0; kc < 2; ++kc) {
        __syncthreads();
        #pragma unroll 8
        for (int it = 0; it < 16; ++it) {
          const int li = it * 256 + tid;
          const int row = li >> 5;
          const int col = (li & 31) * 4;
          const float4 v = *(const float4*)(hsrc + (size_t)row * 256 + kc * 128 + col);
          unsigned short* d = &Abuf[row * 136 + col];
          d[0] = f2bf(v.x); d[1] = f2bf(v.y); d[2] = f2bf(v.z); d[3] = f2bf(v.w);
        }
        __syncthreads();
        // after kc==1 staging barrier, all hbuf reads for this cell are done -> unblock writer
        if (kc == 1 && tid == 0)
          __hip_atomic_fetch_add(&eflag[Le * 31 + r], 1, __ATOMIC_RELEASE, __HIP_MEMORY_SCOPE_AGENT);
        #pragma unroll
        for (int ks = 0; ks < 4; ++ks) {
          const int kofs = ks * 32 + quad * 8;
          s16x8 af[2];
          #pragma unroll
          for (int m2 = 0; m2 < 2; ++m2)
            af[m2] = *(const s16x8*)&Abuf[((wv * 2 + m2) * 16 + l16) * 136 + kofs];
          #pragma unroll
          for (int nt = 0; nt < 17; ++nt) {
            const s16x8 bf = *(const s16x8*)(W3c + (size_t)(nt * 16 + l16) * 256 + kc * 128 + kofs);
            #pragma unroll
            for (int m2 = 0; m2 < 2; ++m2)
              acc[m2][nt] = __builtin_amdgcn_mfma_f32_16x16x32_bf16(af[m2], bf, acc[m2][nt], 0, 0, 0);
          }
        }
      }

      const float* bias = (c == 0) ? red_b : (c == 1) ? green_b : blue_b;
      #pragma unroll
      for (int m2 = 0; m2 < 2; ++m2)
        #pragma unroll
        for (int i = 0; i < 4; ++i) {
          const int b = (m2 + wv * 2) * 16 + quad * 4 + i;
          const int t0 = idx0[b], t1 = idx1[b];
          float* orow = out + ((size_t)((b * 3 + c) * 31 + r) * 31 + k) * 257;
          #pragma unroll
          for (int nt = 0; nt < 17; ++nt) {
            const int v = nt * 16 + l16;
            if (v < 257) {
              float val = acc[m2][nt][i] + bias[v];
              if (c == 1)      val += TG[(size_t)t0 * 257 + v];
              else if (c == 2) val += TB0[(size_t)t0 * 257 + v] + TB1[(size_t)t1 * 257 + v];
              orow[v] = val;
            }
          }
        }
    }
  }
}

// ---------------- host launch ----------------

extern "C" void kernel_launch(void* const* d_in, const int* in_sizes, int n_in,
                              void* d_out, int out_size, void* d_ws, size_t ws_size,
                              hipStream_t stream) {
  const int*   x       = (const int*)  d_in[0];
  const float* emb     = (const float*)d_in[1];
  const float* xcomb_W = (const float*)d_in[2];
  const float* xcomb_b = (const float*)d_in[3];
  const float* hcomb_W = (const float*)d_in[4];
  const float* hcomb_b = (const float*)d_in[5];
  const float* W_ih    = (const float*)d_in[6];
  const float* W_hh    = (const float*)d_in[7];
  const float* b_ih    = (const float*)d_in[8];
  const float* b_hh    = (const float*)d_in[9];
  const float* red_W   = (const float*)d_in[10];
  const float* red_b   = (const float*)d_in[11];
  const float* green_W = (const float*)d_in[12];
  const float* green_b = (const float*)d_in[13];
  const float* blue_W  = (const float*)d_in[14];
  const float* blue_b  = (const float*)d_in[15];
  float* out = (float*)d_out;

  char* p = (char*)d_ws;
  auto alloc = [&](size_t bytes) -> char* {
    char* r = p; p += (bytes + 255) & ~(size_t)255; return r;
  };
  float* hbuf          = (float*)alloc((size_t)31 * 3 * 128 * 256 * 4);
  unsigned short* Wbig = (unsigned short*)alloc((size_t)3 * 1024 * 512 * 2);
  float* bbig          = (float*)alloc((size_t)3 * 1024 * 4);
  float* Tl            = (float*)alloc((size_t)3 * 257 * 768 * 4);
  float* Ta            = (float*)alloc((size_t)3 * 257 * 768 * 4);
  float* Ul            = (float*)alloc((size_t)3 * 257 * 256 * 4);
  float* Ua            = (float*)alloc((size_t)3 * 257 * 256 * 4);
  float* bgx           = (float*)alloc((size_t)3 * 768 * 4);
  unsigned short* W3   = (unsigned short*)alloc((size_t)3 * 272 * 256 * 2);
  float* TG            = (float*)alloc((size_t)257 * 257 * 4);
  float* TB0           = (float*)alloc((size_t)257 * 257 * 4);
  float* TB1           = (float*)alloc((size_t)257 * 257 * 4);
  int*   flags         = (int*)  alloc((size_t)2 * 124 * 31 * 4);
  float* pregx         = (float*)alloc((size_t)2883 * 3 * 128 * 256 * 4);  // 1.13 GB (ws ~1.5 GB)

  prep_wbig<<<dim3(3, 1024), dim3(256), 0, stream>>>(hcomb_W, hcomb_b, W_hh, b_hh, Wbig, bbig);
  prep_u<<<dim3(3, 257, 2), dim3(256), 0, stream>>>(emb, xcomb_W, Ul, Ua);
  prep_t<<<dim3(3, 257, 2), dim3(768), 0, stream>>>(W_ih, Ul, Ua, Tl, Ta);
  prep_bgx<<<dim3(3), dim3(768), 0, stream>>>(W_ih, xcomb_b, b_ih, bgx);
  prep_tgb<<<dim3(257, 3), dim3(320), 0, stream>>>(emb, green_W, blue_W, TG, TB0, TB1);
  prep_w3<<<dim3(3, 272), dim3(256), 0, stream>>>(red_W, green_W, blue_W, W3);
  prep_gx<<<dim3(31, 31, 3), dim3(256), 0, stream>>>(x, Tl, Ta, bgx, bbig, W_ih, pregx);
  zero_flags<<<dim3(31), dim3(256), 0, stream>>>(flags, 2 * 124 * 31);

  // one persistent launch: 155 active blocks (31 rows x {4 step roles + 1 epi}) <= 256 CUs
  persist_kernel<<<dim3(160), dim3(256), 0, stream>>>(
      x, hbuf, Wbig, bbig, pregx, W3, TG, TB0, TB1, red_b, green_b, blue_b, out, flags);
}

// Round 2
// 9558.748 us; speedup vs baseline: 1.0871x; 1.0871x over previous
//
#include <hip/hip_runtime.h>

typedef __attribute__((ext_vector_type(4))) float f32x4;
typedef __attribute__((ext_vector_type(8))) short s16x8;
typedef unsigned long long u64;

__device__ __forceinline__ unsigned short f2bf(float f) {
  union { float f; unsigned u; } v; v.f = f;
  unsigned r = v.u + 0x7fffu + ((v.u >> 16) & 1u);
  return (unsigned short)(r >> 16);
}

// ---------------- prep kernels ----------------

// Wbig[c] (1024x512) = [hcomb_W[c]; W_hh[c] @ hcomb_W[c]] as bf16
// bbig[c] (1024)     = [hcomb_b[c]; W_hh[c] @ hcomb_b[c] + b_hh[c]]
__global__ void prep_wbig(const float* __restrict__ hcomb_W, const float* __restrict__ hcomb_b,
                          const float* __restrict__ W_hh, const float* __restrict__ b_hh,
                          unsigned short* __restrict__ Wbig, float* __restrict__ bbig) {
  __shared__ float red[256];
  const int c = blockIdx.x, g = blockIdx.y, t = threadIdx.x;
  const float* hW = hcomb_W + (size_t)c * 256 * 512;
  unsigned short* orow = Wbig + ((size_t)c * 1024 + g) * 512;
  if (g < 256) {
    orow[t]       = f2bf(hW[(size_t)g * 512 + t]);
    orow[t + 256] = f2bf(hW[(size_t)g * 512 + t + 256]);
    if (t == 0) bbig[c * 1024 + g] = hcomb_b[c * 256 + g];
    return;
  }
  const int gp = g - 256;
  const float* wrow = W_hh + ((size_t)c * 768 + gp) * 256;
  float a0 = 0.f, a1 = 0.f;
  for (int h = 0; h < 256; h++) {
    float w = wrow[h];
    a0 += w * hW[(size_t)h * 512 + t];
    a1 += w * hW[(size_t)h * 512 + t + 256];
  }
  orow[t] = f2bf(a0); orow[t + 256] = f2bf(a1);
  red[t] = wrow[t] * hcomb_b[c * 256 + t];
  __syncthreads();
  for (int s = 128; s > 0; s >>= 1) { if (t < s) red[t] += red[t + s]; __syncthreads(); }
  if (t == 0) bbig[c * 1024 + g] = red[0] + b_hh[c * 768 + gp];
}

// U_{l,a}[c][v][f] = sum_e emb[c][v][e] * xcomb_W[c][f][side*256 + e]
__global__ void prep_u(const float* __restrict__ emb, const float* __restrict__ xcomb_W,
                       float* __restrict__ Ul, float* __restrict__ Ua) {
  __shared__ float er[256];
  const int c = blockIdx.x, v = blockIdx.y, side = blockIdx.z, f = threadIdx.x;
  er[f] = emb[((size_t)c * 257 + v) * 256 + f];
  __syncthreads();
  const float* wrow = xcomb_W + ((size_t)c * 256 + f) * 512 + side * 256;
  float a = 0.f;
  for (int e = 0; e < 256; e++) a += er[e] * wrow[e];
  (side ? Ua : Ul)[((size_t)c * 257 + v) * 256 + f] = a;
}

// T_{l,a}[c][v][g] = sum_f W_ih[c][g][f] * U[c][v][f]
__global__ void prep_t(const float* __restrict__ W_ih, const float* __restrict__ Ul,
                       const float* __restrict__ Ua, float* __restrict__ Tl, float* __restrict__ Ta) {
  __shared__ float ur[256];
  const int c = blockIdx.x, v = blockIdx.y, side = blockIdx.z, g = threadIdx.x; // block 768
  if (g < 256) ur[g] = (side ? Ua : Ul)[((size_t)c * 257 + v) * 256 + g];
  __syncthreads();
  const float* wrow = W_ih + ((size_t)c * 768 + g) * 258;
  float a = 0.f;
  for (int f = 0; f < 256; f++) a += ur[f] * wrow[f];
  (side ? Ta : Tl)[((size_t)c * 257 + v) * 768 + g] = a;
}

// bgx[c][g] = b_ih[c][g] + sum_f W_ih[c][g][f] * xcomb_b[c][f]
__global__ void prep_bgx(const float* __restrict__ W_ih, const float* __restrict__ xcomb_b,
                         const float* __restrict__ b_ih, float* __restrict__ bgx) {
  __shared__ float xb[256];
  const int c = blockIdx.x, g = threadIdx.x; // block 768
  if (g < 256) xb[g] = xcomb_b[c * 256 + g];
  __syncthreads();
  const float* wrow = W_ih + ((size_t)c * 768 + g) * 258;
  float a = b_ih[c * 768 + g];
  for (int f = 0; f < 256; f++) a += xb[f] * wrow[f];
  bgx[c * 768 + g] = a;
}

// TG[v][u]  = emb[0][v] . green_W[u][256:512]
// TB0[v][u] = emb[0][v] . blue_W[u][256:512]
// TB1[v][u] = emb[1][v] . blue_W[u][512:768]
__global__ void prep_tgb(const float* __restrict__ emb, const float* __restrict__ green_W,
                         const float* __restrict__ blue_W,
                         float* __restrict__ TG, float* __restrict__ TB0, float* __restrict__ TB1) {
  __shared__ float er[256];
  const int v = blockIdx.x, which = blockIdx.y, u = threadIdx.x; // block 320
  const int ch = (which == 2) ? 1 : 0;
  if (u < 256) er[u] = emb[((size_t)ch * 257 + v) * 256 + u];
  __syncthreads();
  if (u >= 257) return;
  const float* W; int pitch, off; float* T;
  if (which == 0)      { W = green_W; pitch = 512; off = 256; T = TG;  }
  else if (which == 1) { W = blue_W;  pitch = 768; off = 256; T = TB0; }
  else                 { W = blue_W;  pitch = 768; off = 512; T = TB1; }
  const float* wrow = W + (size_t)u * pitch + off;
  float a = 0.f;
  for (int e = 0; e < 256; e++) a += er[e] * wrow[e];
  T[(size_t)v * 257 + u] = a;
}

// W3[c] (272x256) bf16 = h-part of {red_W, green_W, blue_W}; rows >=257 zero
__global__ void prep_w3(const float* __restrict__ red_W, const float* __restrict__ green_W,
                        const float* __restrict__ blue_W, unsigned short* __restrict__ W3) {
  const int c = blockIdx.x, v = blockIdx.y, t = threadIdx.x; // block 256
  float val = 0.f;
  if (v < 257) {
    if (c == 0)      val = red_W[(size_t)v * 256 + t];
    else if (c == 1) val = green_W[(size_t)v * 512 + t];
    else             val = blue_W[(size_t)v * 768 + t];
  }
  W3[((size_t)c * 272 + v) * 256 + t] = f2bf(val);
}

// materialize per-cell gate-x preactivations (index-static, BW-bound, off critical path)
// pregx[cell][gate(3)][b(128)][j(256)]; gates r,z include their gh biases; gate n excludes bn.
__global__ void prep_gx(const int* __restrict__ x,
                        const float* __restrict__ Tl, const float* __restrict__ Ta,
                        const float* __restrict__ bgx, const float* __restrict__ bbig,
                        const float* __restrict__ W_ih, float* __restrict__ pregx) {
  __shared__ float base[768];
  __shared__ int ix0[128], ix1[128];
  const int r = blockIdx.x, k = blockIdx.y, c = blockIdx.z, tid = threadIdx.x; // block 256
  for (int g = tid; g < 768; g += 256) {
    float v = bgx[c * 768 + g]
            + (float)r * W_ih[((size_t)c * 768 + g) * 258 + 256]
            + (float)k * W_ih[((size_t)c * 768 + g) * 258 + 257];
    if (g < 512) v += bbig[c * 1024 + 256 + g];   // br / bz folded in
    base[g] = v;
  }
  if (tid < 128) {
    ix0[tid] = x[((tid * 3 + c) * 32 + (r + 1)) * 32 + k];       // left index
    ix1[tid] = x[((tid * 3 + c) * 32 + r) * 32 + (k + 1)];       // above index
  }
  __syncthreads();
  const size_t cell = ((size_t)(r * 31 + k)) * 3 + c;
  float* outp = pregx + cell * 3 * 128 * 256;
  const float* Tlc = Tl + (size_t)c * 257 * 768;
  const float* Tac = Ta + (size_t)c * 257 * 768;
  #pragma unroll 2
  for (int b = 0; b < 128; ++b) {
    const float* tl = Tlc + (size_t)ix0[b] * 768;
    const float* ta = Tac + (size_t)ix1[b] * 768;
    #pragma unroll
    for (int q = 0; q < 3; ++q) {
      const int g = q * 256 + tid;
      outp[((size_t)q * 128 + b) * 256 + tid] = tl[g] + ta[g] + base[g];
    }
  }
}

__global__ void zero_flags(int* __restrict__ f, int n) {
  int i = blockIdx.x * 256 + threadIdx.x;
  if (i < n) f[i] = 0;
}

// ---------------- persistent wavefront kernel ----------------
// sflag[L][r]: 4 role blocks of row r post (release/agent) after writing h at level L.
// eflag[Le][r]: epi block r posts (relaxed; barrier already drained its reads).
// Coherence scheme: NO agent acquire fence (buffer_inv nuked L2 every iter = round-1 failure).
// Instead: hbuf hand-off loads are system-scope relaxed 8B atomic loads (sc0 sc1 -> read L3
// directly, bypassing stale XCD-local L1/L2). Producer release fetch_add does buffer_wbl2
// (writeback, keeps caches warm). Weights/pregx stay L2-resident across all iterations.

__device__ __forceinline__ void spinwait(int* f, int target) {
  while (__hip_atomic_load(f, __ATOMIC_RELAXED, __HIP_MEMORY_SCOPE_AGENT) < target)
    __builtin_amdgcn_s_sleep(2);
}

__device__ __forceinline__ u64 load_coh(const float* p) {
  return __hip_atomic_load((const u64*)p, __ATOMIC_RELAXED, __HIP_MEMORY_SCOPE_SYSTEM);
}

__global__ __launch_bounds__(256, 2)
void persist_kernel(const int* __restrict__ x, float* __restrict__ hbuf,
                    const unsigned short* __restrict__ Wbig, const float* __restrict__ bbig,
                    const float* __restrict__ pregx,
                    const unsigned short* __restrict__ W3,
                    const float* __restrict__ TG, const float* __restrict__ TB0,
                    const float* __restrict__ TB1,
                    const float* __restrict__ red_b, const float* __restrict__ green_b,
                    const float* __restrict__ blue_b,
                    float* __restrict__ out, int* __restrict__ flags)
{
  __shared__ unsigned short Abuf[128 * 136];
  __shared__ int idx0[128], idx1[128];

  // XCD swizzle: all 5 blocks of row r share (id & 7) -> same XCD under %8 round-robin.
  const int id = blockIdx.x;
  const int rlo = id & 7, slot = id >> 3;
  const int rhi = slot / 5, role = slot - 5 * rhi;
  const int r = rlo + 8 * rhi;
  if (r > 30) return;

  int* sflag = flags;              // [124][31]
  int* eflag = flags + 124 * 31;   // [124][31]

  const int tid = threadIdx.x;
  const int lane = tid & 63, wv = tid >> 6;
  const int quad = lane >> 4, l16 = lane & 15;

  if (role < 4) {
    // ---------------- recurrent step: row r, levels L = r .. r+92 ----------------
    const int jcol = role * 64 + wv * 16;
    const int j = jcol + l16;

    for (int L = r; L <= r + 92; ++L) {
      const int t = L - r;
      const int k = t / 3, c = t - 3 * k;
      const size_t cell = ((size_t)(r * 31 + k)) * 3 + c;
      const float* pg = pregx + cell * 3 * 128 * 256;

      // acc C-init from pregx (cached loads, independent of flags -> overlap the spin)
      f32x4 acc[8][4];
      const float bh  = bbig[c * 1024 + j];
      const float bn3 = bbig[c * 1024 + 768 + j];
      #pragma unroll
      for (int mt = 0; mt < 8; ++mt)
        #pragma unroll
        for (int i = 0; i < 4; ++i) {
          const int b = mt * 16 + quad * 4 + i;
          acc[mt][0][i] = bh;                                   // h bias
          acc[mt][1][i] = pg[(size_t)b * 256 + j];              // gxr + br
          acc[mt][2][i] = pg[(size_t)(128 + b) * 256 + j];      // gxz + bz
          acc[mt][3][i] = bn3;                                  // bn (inside r* term)
        }

      // wait for producers / consumers of the hbuf slots we touch
      if (tid == 0) {
        if (t >= 1) spinwait(&sflag[(L - 1) * 31 + r], 4);
        if (r >= 1) spinwait(&sflag[(L - 1) * 31 + (r - 1)], 4);
        if (t >= 3) {
          if (r < 30) spinwait(&sflag[(L - 2) * 31 + (r + 1)], 4);
          spinwait(&eflag[(L - 2) * 31 + r], 1);
        }
      }
      __syncthreads();
      __builtin_amdgcn_fence(__ATOMIC_ACQUIRE, "workgroup"); // compiler barrier; no buffer_inv

      const bool pl_zero = (t == 0);
      const bool a_zero  = (r == 0);
      const float* plp = hbuf + ((size_t)(r * 3 + (c == 0 ? 2 : c - 1)) * 128) * 256;
      const float* ap  = (r > 0) ? hbuf + ((size_t)((r - 1) * 3 + c) * 128) * 256 : hbuf;
      const unsigned short* Wb = Wbig + (size_t)c * 1024 * 512;

      for (int kc = 0; kc < 4; ++kc) {
        const bool from_pl = (kc < 2);
        const float* src = from_pl ? plp : ap;
        const bool zero = from_pl ? pl_zero : a_zero;
        const int colbase = from_pl ? kc * 128 : (kc - 2) * 128;
        __syncthreads();
        #pragma unroll 8
        for (int it = 0; it < 16; ++it) {
          const int li = it * 256 + tid;
          const int row = li >> 5;
          const int col = (li & 31) * 4;
          u64 q0 = 0, q1 = 0;
          if (!zero) {
            const float* sp = src + (size_t)row * 256 + colbase + col;
            q0 = load_coh(sp);
            q1 = load_coh(sp + 2);
          }
          union { u64 q; float f[2]; } a0, a1; a0.q = q0; a1.q = q1;
          union { unsigned short s[4]; u64 q; } o;
          o.s[0] = f2bf(a0.f[0]); o.s[1] = f2bf(a0.f[1]);
          o.s[2] = f2bf(a1.f[0]); o.s[3] = f2bf(a1.f[1]);
          *(u64*)&Abuf[row * 136 + col] = o.q;
        }
        __syncthreads();
        #pragma unroll
        for (int ks = 0; ks < 4; ++ks) {
          const int kofs = ks * 32 + quad * 8;
          s16x8 bf[4];
          #pragma unroll
          for (int g = 0; g < 4; ++g)
            bf[g] = *(const s16x8*)(Wb + (size_t)(g * 256 + jcol + l16) * 512 + kc * 128 + kofs);
          #pragma unroll
          for (int mt = 0; mt < 8; ++mt) {
            const s16x8 af = *(const s16x8*)&Abuf[(mt * 16 + l16) * 136 + kofs];
            #pragma unroll
            for (int g = 0; g < 4; ++g)
              acc[mt][g] = __builtin_amdgcn_mfma_f32_16x16x32_bf16(af, bf[g], acc[mt][g], 0, 0, 0);
          }
        }
      }

      // GRU epilogue: acc[0]=h, acc[1]=gxr+ghr, acc[2]=gxz+ghz, acc[3]=ghn
      const float* pgn = pg + (size_t)2 * 128 * 256;
      float* hout = hbuf + ((size_t)(r * 3 + c) * 128) * 256;
      #pragma unroll
      for (int mt = 0; mt < 8; ++mt)
        #pragma unroll
        for (int i = 0; i < 4; ++i) {
          const int b = mt * 16 + quad * 4 + i;
          const float gxn = pgn[(size_t)b * 256 + j];
          const float h  = acc[mt][0][i];
          const float rg = __fdividef(1.f, 1.f + __expf(-acc[mt][1][i]));
          const float zg = __fdividef(1.f, 1.f + __expf(-acc[mt][2][i]));
          const float ng = 1.f - __fdividef(2.f, __expf(2.f * (gxn + rg * acc[mt][3][i])) + 1.f);
          hout[(size_t)b * 256 + j] = (1.f - zg) * ng + zg * h;
        }

      __syncthreads();   // all threads' h stores drained (barrier implies vmcnt(0))
      if (tid == 0)
        __hip_atomic_fetch_add(&sflag[L * 31 + r], 1, __ATOMIC_RELEASE, __HIP_MEMORY_SCOPE_AGENT);
    }
  } else {
    // ---------------- logits epilogue: row r, iters Le = r+1 .. r+93 (cell level Le-1) ----------------
    for (int Le = r + 1; Le <= r + 93; ++Le) {
      const int t = Le - 1 - r;
      const int k = t / 3, c = t - 3 * k;

      if (tid < 128) {
        idx0[tid] = x[((tid * 3 + 0) * 32 + (r + 1)) * 32 + (k + 1)];  // target ch0
        idx1[tid] = x[((tid * 3 + 1) * 32 + (r + 1)) * 32 + (k + 1)];  // target ch1
      }

      if (tid == 0) spinwait(&sflag[(Le - 1) * 31 + r], 4);
      __syncthreads();
      __builtin_amdgcn_fence(__ATOMIC_ACQUIRE, "workgroup"); // compiler barrier; no buffer_inv

      const float* hsrc = hbuf + ((size_t)(r * 3 + c) * 128) * 256;
      const unsigned short* W3c = W3 + (size_t)c * 272 * 256;

      f32x4 acc[2][17];
      #pragma unroll
      for (int m2 = 0; m2 < 2; ++m2)
        #pragma unroll
        for (int nt = 0; nt < 17; ++nt)
          #pragma unroll
          for (int e = 0; e < 4; ++e) acc[m2][nt][e] = 0.f;

      for (int kc = 0; kc < 2; ++kc) {
        __syncthreads();
        #pragma unroll 8
        for (int it = 0; it < 16; ++it) {
          const int li = it * 256 + tid;
          const int row = li >> 5;
          const int col = (li & 31) * 4;
          const float* sp = hsrc + (size_t)row * 256 + kc * 128 + col;
          union { u64 q; float f[2]; } a0, a1;
          a0.q = load_coh(sp);
          a1.q = load_coh(sp + 2);
          union { unsigned short s[4]; u64 q; } o;
          o.s[0] = f2bf(a0.f[0]); o.s[1] = f2bf(a0.f[1]);
          o.s[2] = f2bf(a1.f[0]); o.s[3] = f2bf(a1.f[1]);
          *(u64*)&Abuf[row * 136 + col] = o.q;
        }
        __syncthreads();
        // after kc==1 staging barrier all hbuf reads for this cell are done -> unblock writer
        // (barrier drained vmcnt, so relaxed post is safe)
        if (kc == 1 && tid == 0)
          __hip_atomic_fetch_add(&eflag[Le * 31 + r], 1, __ATOMIC_RELAXED, __HIP_MEMORY_SCOPE_AGENT);
        #pragma unroll
        for (int ks = 0; ks < 4; ++ks) {
          const int kofs = ks * 32 + quad * 8;
          s16x8 af[2];
          #pragma unroll
          for (int m2 = 0; m2 < 2; ++m2)
            af[m2] = *(const s16x8*)&Abuf[((wv * 2 + m2) * 16 + l16) * 136 + kofs];
          #pragma unroll
          for (int nt = 0; nt < 17; ++nt) {
            const s16x8 bf = *(const s16x8*)(W3c + (size_t)(nt * 16 + l16) * 256 + kc * 128 + kofs);
            #pragma unroll
            for (int m2 = 0; m2 < 2; ++m2)
              acc[m2][nt] = __builtin_amdgcn_mfma_f32_16x16x32_bf16(af[m2], bf, acc[m2][nt], 0, 0, 0);
          }
        }
      }

      const float* bias = (c == 0) ? red_b : (c == 1) ? green_b : blue_b;
      #pragma unroll
      for (int m2 = 0; m2 < 2; ++m2)
        #pragma unroll
        for (int i = 0; i < 4; ++i) {
          const int b = (m2 + wv * 2) * 16 + quad * 4 + i;
          const int t0 = idx0[b], t1 = idx1[b];
          float* orow = out + ((size_t)((b * 3 + c) * 31 + r) * 31 + k) * 257;
          #pragma unroll
          for (int nt = 0; nt < 17; ++nt) {
            const int v = nt * 16 + l16;
            if (v < 257) {
              float val = acc[m2][nt][i] + bias[v];
              if (c == 1)      val += TG[(size_t)t0 * 257 + v];
              else if (c == 2) val += TB0[(size_t)t0 * 257 + v] + TB1[(size_t)t1 * 257 + v];
              orow[v] = val;
            }
          }
        }
    }
  }
}

// ---------------- host launch ----------------

extern "C" void kernel_launch(void* const* d_in, const int* in_sizes, int n_in,
                              void* d_out, int out_size, void* d_ws, size_t ws_size,
                              hipStream_t stream) {
  const int*   x       = (const int*)  d_in[0];
  const float* emb     = (const float*)d_in[1];
  const float* xcomb_W = (const float*)d_in[2];
  const float* xcomb_b = (const float*)d_in[3];
  const float* hcomb_W = (const float*)d_in[4];
  const float* hcomb_b = (const float*)d_in[5];
  const float* W_ih    = (const float*)d_in[6];
  const float* W_hh    = (const float*)d_in[7];
  const float* b_ih    = (const float*)d_in[8];
  const float* b_hh    = (const float*)d_in[9];
  const float* red_W   = (const float*)d_in[10];
  const float* red_b   = (const float*)d_in[11];
  const float* green_W = (const float*)d_in[12];
  const float* green_b = (const float*)d_in[13];
  const float* blue_W  = (const float*)d_in[14];
  const float* blue_b  = (const float*)d_in[15];
  float* out = (float*)d_out;

  char* p = (char*)d_ws;
  auto alloc = [&](size_t bytes) -> char* {
    char* r = p; p += (bytes + 255) & ~(size_t)255; return r;
  };
  float* hbuf          = (float*)alloc((size_t)31 * 3 * 128 * 256 * 4);
  unsigned short* Wbig = (unsigned short*)alloc((size_t)3 * 1024 * 512 * 2);
  float* bbig          = (float*)alloc((size_t)3 * 1024 * 4);
  float* Tl            = (float*)alloc((size_t)3 * 257 * 768 * 4);
  float* Ta            = (float*)alloc((size_t)3 * 257 * 768 * 4);
  float* Ul            = (float*)alloc((size_t)3 * 257 * 256 * 4);
  float* Ua            = (float*)alloc((size_t)3 * 257 * 256 * 4);
  float* bgx           = (float*)alloc((size_t)3 * 768 * 4);
  unsigned short* W3   = (unsigned short*)alloc((size_t)3 * 272 * 256 * 2);
  float* TG            = (float*)alloc((size_t)257 * 257 * 4);
  float* TB0           = (float*)alloc((size_t)257 * 257 * 4);
  float* TB1           = (float*)alloc((size_t)257 * 257 * 4);
  int*   flags         = (int*)  alloc((size_t)2 * 124 * 31 * 4);
  float* pregx         = (float*)alloc((size_t)2883 * 3 * 128 * 256 * 4);  // 1.13 GB

  prep_wbig<<<dim3(3, 1024), dim3(256), 0, stream>>>(hcomb_W, hcomb_b, W_hh, b_hh, Wbig, bbig);
  prep_u<<<dim3(3, 257, 2), dim3(256), 0, stream>>>(emb, xcomb_W, Ul, Ua);
  prep_t<<<dim3(3, 257, 2), dim3(768), 0, stream>>>(W_ih, Ul, Ua, Tl, Ta);
  prep_bgx<<<dim3(3), dim3(768), 0, stream>>>(W_ih, xcomb_b, b_ih, bgx);
  prep_tgb<<<dim3(257, 3), dim3(320), 0, stream>>>(emb, green_W, blue_W, TG, TB0, TB1);
  prep_w3<<<dim3(3, 272), dim3(256), 0, stream>>>(red_W, green_W, blue_W, W3);
  prep_gx<<<dim3(31, 31, 3), dim3(256), 0, stream>>>(x, Tl, Ta, bgx, bbig, W_ih, pregx);
  zero_flags<<<dim3(31), dim3(256), 0, stream>>>(flags, 2 * 124 * 31);

  // one persistent launch: 155 active blocks (31 rows x {4 step roles + 1 epi}) <= 256 CUs
  persist_kernel<<<dim3(160), dim3(256), 0, stream>>>(
      x, hbuf, Wbig, bbig, pregx, W3, TG, TB0, TB1, red_b, green_b, blue_b, out, flags);
}

// Round 3
// 9158.942 us; speedup vs baseline: 1.1345x; 1.0437x over previous
//
#include <hip/hip_runtime.h>

typedef __attribute__((ext_vector_type(4))) float f32x4;
typedef __attribute__((ext_vector_type(8))) short s16x8;
typedef unsigned long long u64;

__device__ __forceinline__ unsigned short f2bf(float f) {
  union { float f; unsigned u; } v; v.f = f;
  unsigned r = v.u + 0x7fffu + ((v.u >> 16) & 1u);
  return (unsigned short)(r >> 16);
}

// ---------------- prep kernels ----------------

// Wbig[c] (1024x512) = [hcomb_W[c]; W_hh[c] @ hcomb_W[c]] as bf16
// bbig[c] (1024)     = [hcomb_b[c]; W_hh[c] @ hcomb_b[c] + b_hh[c]]
__global__ void prep_wbig(const float* __restrict__ hcomb_W, const float* __restrict__ hcomb_b,
                          const float* __restrict__ W_hh, const float* __restrict__ b_hh,
                          unsigned short* __restrict__ Wbig, float* __restrict__ bbig) {
  __shared__ float red[256];
  const int c = blockIdx.x, g = blockIdx.y, t = threadIdx.x;
  const float* hW = hcomb_W + (size_t)c * 256 * 512;
  unsigned short* orow = Wbig + ((size_t)c * 1024 + g) * 512;
  if (g < 256) {
    orow[t]       = f2bf(hW[(size_t)g * 512 + t]);
    orow[t + 256] = f2bf(hW[(size_t)g * 512 + t + 256]);
    if (t == 0) bbig[c * 1024 + g] = hcomb_b[c * 256 + g];
    return;
  }
  const int gp = g - 256;
  const float* wrow = W_hh + ((size_t)c * 768 + gp) * 256;
  float a0 = 0.f, a1 = 0.f;
  for (int h = 0; h < 256; h++) {
    float w = wrow[h];
    a0 += w * hW[(size_t)h * 512 + t];
    a1 += w * hW[(size_t)h * 512 + t + 256];
  }
  orow[t] = f2bf(a0); orow[t + 256] = f2bf(a1);
  red[t] = wrow[t] * hcomb_b[c * 256 + t];
  __syncthreads();
  for (int s = 128; s > 0; s >>= 1) { if (t < s) red[t] += red[t + s]; __syncthreads(); }
  if (t == 0) bbig[c * 1024 + g] = red[0] + b_hh[c * 768 + gp];
}

// U_{l,a}[c][v][f] = sum_e emb[c][v][e] * xcomb_W[c][f][side*256 + e]
__global__ void prep_u(const float* __restrict__ emb, const float* __restrict__ xcomb_W,
                       float* __restrict__ Ul, float* __restrict__ Ua) {
  __shared__ float er[256];
  const int c = blockIdx.x, v = blockIdx.y, side = blockIdx.z, f = threadIdx.x;
  er[f] = emb[((size_t)c * 257 + v) * 256 + f];
  __syncthreads();
  const float* wrow = xcomb_W + ((size_t)c * 256 + f) * 512 + side * 256;
  float a = 0.f;
  for (int e = 0; e < 256; e++) a += er[e] * wrow[e];
  (side ? Ua : Ul)[((size_t)c * 257 + v) * 256 + f] = a;
}

// T_{l,a}[c][v][g] = sum_f W_ih[c][g][f] * U[c][v][f]
__global__ void prep_t(const float* __restrict__ W_ih, const float* __restrict__ Ul,
                       const float* __restrict__ Ua, float* __restrict__ Tl, float* __restrict__ Ta) {
  __shared__ float ur[256];
  const int c = blockIdx.x, v = blockIdx.y, side = blockIdx.z, g = threadIdx.x; // block 768
  if (g < 256) ur[g] = (side ? Ua : Ul)[((size_t)c * 257 + v) * 256 + g];
  __syncthreads();
  const float* wrow = W_ih + ((size_t)c * 768 + g) * 258;
  float a = 0.f;
  for (int f = 0; f < 256; f++) a += ur[f] * wrow[f];
  (side ? Ta : Tl)[((size_t)c * 257 + v) * 768 + g] = a;
}

// bgx[c][g] = b_ih[c][g] + sum_f W_ih[c][g][f] * xcomb_b[c][f]
__global__ void prep_bgx(const float* __restrict__ W_ih, const float* __restrict__ xcomb_b,
                         const float* __restrict__ b_ih, float* __restrict__ bgx) {
  __shared__ float xb[256];
  const int c = blockIdx.x, g = threadIdx.x; // block 768
  if (g < 256) xb[g] = xcomb_b[c * 256 + g];
  __syncthreads();
  const float* wrow = W_ih + ((size_t)c * 768 + g) * 258;
  float a = b_ih[c * 768 + g];
  for (int f = 0; f < 256; f++) a += xb[f] * wrow[f];
  bgx[c * 768 + g] = a;
}

// TG[v][u]  = emb[0][v] . green_W[u][256:512]
// TB0[v][u] = emb[0][v] . blue_W[u][256:512]
// TB1[v][u] = emb[1][v] . blue_W[u][512:768]
__global__ void prep_tgb(const float* __restrict__ emb, const float* __restrict__ green_W,
                         const float* __restrict__ blue_W,
                         float* __restrict__ TG, float* __restrict__ TB0, float* __restrict__ TB1) {
  __shared__ float er[256];
  const int v = blockIdx.x, which = blockIdx.y, u = threadIdx.x; // block 320
  const int ch = (which == 2) ? 1 : 0;
  if (u < 256) er[u] = emb[((size_t)ch * 257 + v) * 256 + u];
  __syncthreads();
  if (u >= 257) return;
  const float* W; int pitch, off; float* T;
  if (which == 0)      { W = green_W; pitch = 512; off = 256; T = TG;  }
  else if (which == 1) { W = blue_W;  pitch = 768; off = 256; T = TB0; }
  else                 { W = blue_W;  pitch = 768; off = 512; T = TB1; }
  const float* wrow = W + (size_t)u * pitch + off;
  float a = 0.f;
  for (int e = 0; e < 256; e++) a += er[e] * wrow[e];
  T[(size_t)v * 257 + u] = a;
}

// W3[c] (272x256) bf16 = h-part of {red_W, green_W, blue_W}; rows >=257 zero
__global__ void prep_w3(const float* __restrict__ red_W, const float* __restrict__ green_W,
                        const float* __restrict__ blue_W, unsigned short* __restrict__ W3) {
  const int c = blockIdx.x, v = blockIdx.y, t = threadIdx.x; // block 256
  float val = 0.f;
  if (v < 257) {
    if (c == 0)      val = red_W[(size_t)v * 256 + t];
    else if (c == 1) val = green_W[(size_t)v * 512 + t];
    else             val = blue_W[(size_t)v * 768 + t];
  }
  W3[((size_t)c * 272 + v) * 256 + t] = f2bf(val);
}

// materialize per-cell gate-x preactivations (index-static, BW-bound, off critical path)
// pregx[cell][gate(3)][b(128)][j(256)]; gates r,z include their gh biases; gate n excludes bn.
__global__ void prep_gx(const int* __restrict__ x,
                        const float* __restrict__ Tl, const float* __restrict__ Ta,
                        const float* __restrict__ bgx, const float* __restrict__ bbig,
                        const float* __restrict__ W_ih, float* __restrict__ pregx) {
  __shared__ float base[768];
  __shared__ int ix0[128], ix1[128];
  const int r = blockIdx.x, k = blockIdx.y, c = blockIdx.z, tid = threadIdx.x; // block 256
  for (int g = tid; g < 768; g += 256) {
    float v = bgx[c * 768 + g]
            + (float)r * W_ih[((size_t)c * 768 + g) * 258 + 256]
            + (float)k * W_ih[((size_t)c * 768 + g) * 258 + 257];
    if (g < 512) v += bbig[c * 1024 + 256 + g];   // br / bz folded in
    base[g] = v;
  }
  if (tid < 128) {
    ix0[tid] = x[((tid * 3 + c) * 32 + (r + 1)) * 32 + k];       // left index
    ix1[tid] = x[((tid * 3 + c) * 32 + r) * 32 + (k + 1)];       // above index
  }
  __syncthreads();
  const size_t cell = ((size_t)(r * 31 + k)) * 3 + c;
  float* outp = pregx + cell * 3 * 128 * 256;
  const float* Tlc = Tl + (size_t)c * 257 * 768;
  const float* Tac = Ta + (size_t)c * 257 * 768;
  #pragma unroll 2
  for (int b = 0; b < 128; ++b) {
    const float* tl = Tlc + (size_t)ix0[b] * 768;
    const float* ta = Tac + (size_t)ix1[b] * 768;
    #pragma unroll
    for (int q = 0; q < 3; ++q) {
      const int g = q * 256 + tid;
      outp[((size_t)q * 128 + b) * 256 + tid] = tl[g] + ta[g] + base[g];
    }
  }
}

__global__ void zero_flags(int* __restrict__ f, int n) {
  int i = blockIdx.x * 256 + threadIdx.x;
  if (i < n) f[i] = 0;
}

// ---------------- persistent wavefront kernel ----------------
// Coherence scheme (NO cache-maintenance ops in the loop — wbl2/inv storms were the
// round-1/2 failure):
//   - h stores: write-through system-scope relaxed atomic stores (sc0 sc1 -> land in L3).
//   - h loads:  system-scope relaxed atomic loads (sc0 sc1 -> read L3, bypass stale L1/L2).
//   - sflag/eflag posts: RELAXED agent-scope fetch_add (sc1 atomic at L3; no buffer_wbl2).
//     Ordering: __syncthreads() before the post drains vmcnt(0) -> write-through h stores
//     are complete at L3 before the flag becomes visible.
//   - spins: relaxed agent loads; consumer data loads are control-dependent + wg acquire.

__device__ __forceinline__ void spinwait(int* f, int target) {
  while (__hip_atomic_load(f, __ATOMIC_RELAXED, __HIP_MEMORY_SCOPE_AGENT) < target)
    __builtin_amdgcn_s_sleep(2);
}

__device__ __forceinline__ u64 load_coh(const float* p) {
  return __hip_atomic_load((const u64*)p, __ATOMIC_RELAXED, __HIP_MEMORY_SCOPE_SYSTEM);
}

__device__ __forceinline__ void store_coh(float* p, float v) {
  __hip_atomic_store(p, v, __ATOMIC_RELAXED, __HIP_MEMORY_SCOPE_SYSTEM);
}

__global__ __launch_bounds__(256, 2)
void persist_kernel(const int* __restrict__ x, float* __restrict__ hbuf,
                    const unsigned short* __restrict__ Wbig, const float* __restrict__ bbig,
                    const float* __restrict__ pregx,
                    const unsigned short* __restrict__ W3,
                    const float* __restrict__ TG, const float* __restrict__ TB0,
                    const float* __restrict__ TB1,
                    const float* __restrict__ red_b, const float* __restrict__ green_b,
                    const float* __restrict__ blue_b,
                    float* __restrict__ out, int* __restrict__ flags)
{
  __shared__ unsigned short Abuf[128 * 136];
  __shared__ int idx0[128], idx1[128];

  // XCD swizzle: all 5 blocks of row r share (id & 7) -> same XCD under %8 round-robin.
  const int id = blockIdx.x;
  const int rlo = id & 7, slot = id >> 3;
  const int rhi = slot / 5, role = slot - 5 * rhi;
  const int r = rlo + 8 * rhi;
  if (r > 30) return;

  int* sflag = flags;              // [124][31]
  int* eflag = flags + 124 * 31;   // [124][31]

  const int tid = threadIdx.x;
  const int lane = tid & 63, wv = tid >> 6;
  const int quad = lane >> 4, l16 = lane & 15;

  if (role < 4) {
    // ---------------- recurrent step: row r, levels L = r .. r+92 ----------------
    const int jcol = role * 64 + wv * 16;
    const int j = jcol + l16;

    for (int L = r; L <= r + 92; ++L) {
      const int t = L - r;
      const int k = t / 3, c = t - 3 * k;
      const size_t cell = ((size_t)(r * 31 + k)) * 3 + c;
      const float* pg = pregx + cell * 3 * 128 * 256;
      const float* pgn = pg + (size_t)2 * 128 * 256;

      // acc C-init + pgn prefetch from pregx (cached loads, flag-independent -> overlap spin)
      f32x4 acc[8][4];
      float pgn_reg[8][4];
      const float bh  = bbig[c * 1024 + j];
      const float bn3 = bbig[c * 1024 + 768 + j];
      #pragma unroll
      for (int mt = 0; mt < 8; ++mt)
        #pragma unroll
        for (int i = 0; i < 4; ++i) {
          const int b = mt * 16 + quad * 4 + i;
          acc[mt][0][i] = bh;                                   // h bias
          acc[mt][1][i] = pg[(size_t)b * 256 + j];              // gxr + br
          acc[mt][2][i] = pg[(size_t)(128 + b) * 256 + j];      // gxz + bz
          acc[mt][3][i] = bn3;                                  // bn (inside r* term)
          pgn_reg[mt][i] = pgn[(size_t)b * 256 + j];            // gxn
        }

      // wait for producers / consumers of the hbuf slots we touch
      if (tid == 0) {
        if (t >= 1) spinwait(&sflag[(L - 1) * 31 + r], 4);
        if (r >= 1) spinwait(&sflag[(L - 1) * 31 + (r - 1)], 4);
        if (t >= 3) {
          if (r < 30) spinwait(&sflag[(L - 2) * 31 + (r + 1)], 4);
          spinwait(&eflag[(L - 2) * 31 + r], 1);
        }
      }
      __syncthreads();
      __builtin_amdgcn_fence(__ATOMIC_ACQUIRE, "workgroup"); // compiler barrier; no buffer_inv

      const bool pl_zero = (t == 0);
      const bool a_zero  = (r == 0);
      const float* plp = hbuf + ((size_t)(r * 3 + (c == 0 ? 2 : c - 1)) * 128) * 256;
      const float* ap  = (r > 0) ? hbuf + ((size_t)((r - 1) * 3 + c) * 128) * 256 : hbuf;
      const unsigned short* Wb = Wbig + (size_t)c * 1024 * 512;

      for (int kc = 0; kc < 4; ++kc) {
        const bool from_pl = (kc < 2);
        const float* src = from_pl ? plp : ap;
        const bool zero = from_pl ? pl_zero : a_zero;
        const int colbase = from_pl ? kc * 128 : (kc - 2) * 128;
        __syncthreads();
        #pragma unroll 8
        for (int it = 0; it < 16; ++it) {
          const int li = it * 256 + tid;
          const int row = li >> 5;
          const int col = (li & 31) * 4;
          u64 q0 = 0, q1 = 0;
          if (!zero) {
            const float* sp = src + (size_t)row * 256 + colbase + col;
            q0 = load_coh(sp);
            q1 = load_coh(sp + 2);
          }
          union { u64 q; float f[2]; } a0, a1; a0.q = q0; a1.q = q1;
          union { unsigned short s[4]; u64 q; } o;
          o.s[0] = f2bf(a0.f[0]); o.s[1] = f2bf(a0.f[1]);
          o.s[2] = f2bf(a1.f[0]); o.s[3] = f2bf(a1.f[1]);
          *(u64*)&Abuf[row * 136 + col] = o.q;
        }
        __syncthreads();
        #pragma unroll
        for (int ks = 0; ks < 4; ++ks) {
          const int kofs = ks * 32 + quad * 8;
          s16x8 bf[4];
          #pragma unroll
          for (int g = 0; g < 4; ++g)
            bf[g] = *(const s16x8*)(Wb + (size_t)(g * 256 + jcol + l16) * 512 + kc * 128 + kofs);
          #pragma unroll
          for (int mt = 0; mt < 8; ++mt) {
            const s16x8 af = *(const s16x8*)&Abuf[(mt * 16 + l16) * 136 + kofs];
            #pragma unroll
            for (int g = 0; g < 4; ++g)
              acc[mt][g] = __builtin_amdgcn_mfma_f32_16x16x32_bf16(af, bf[g], acc[mt][g], 0, 0, 0);
          }
        }
      }

      // GRU epilogue: acc[0]=h, acc[1]=gxr+ghr, acc[2]=gxz+ghz, acc[3]=ghn
      float* hout = hbuf + ((size_t)(r * 3 + c) * 128) * 256;
      #pragma unroll
      for (int mt = 0; mt < 8; ++mt)
        #pragma unroll
        for (int i = 0; i < 4; ++i) {
          const int b = mt * 16 + quad * 4 + i;
          const float gxn = pgn_reg[mt][i];
          const float h  = acc[mt][0][i];
          const float rg = __fdividef(1.f, 1.f + __expf(-acc[mt][1][i]));
          const float zg = __fdividef(1.f, 1.f + __expf(-acc[mt][2][i]));
          const float ng = 1.f - __fdividef(2.f, __expf(2.f * (gxn + rg * acc[mt][3][i])) + 1.f);
          store_coh(&hout[(size_t)b * 256 + j], (1.f - zg) * ng + zg * h);
        }

      __syncthreads();   // drains vmcnt(0): write-through h stores complete at L3
      if (tid == 0)
        __hip_atomic_fetch_add(&sflag[L * 31 + r], 1, __ATOMIC_RELAXED, __HIP_MEMORY_SCOPE_AGENT);
    }
  } else {
    // ---------------- logits epilogue: row r, iters Le = r+1 .. r+93 (cell level Le-1) ----------------
    for (int Le = r + 1; Le <= r + 93; ++Le) {
      const int t = Le - 1 - r;
      const int k = t / 3, c = t - 3 * k;

      if (tid < 128) {
        idx0[tid] = x[((tid * 3 + 0) * 32 + (r + 1)) * 32 + (k + 1)];  // target ch0
        idx1[tid] = x[((tid * 3 + 1) * 32 + (r + 1)) * 32 + (k + 1)];  // target ch1
      }

      if (tid == 0) spinwait(&sflag[(Le - 1) * 31 + r], 4);
      __syncthreads();
      __builtin_amdgcn_fence(__ATOMIC_ACQUIRE, "workgroup"); // compiler barrier; no buffer_inv

      const float* hsrc = hbuf + ((size_t)(r * 3 + c) * 128) * 256;
      const unsigned short* W3c = W3 + (size_t)c * 272 * 256;

      f32x4 acc[2][17];
      #pragma unroll
      for (int m2 = 0; m2 < 2; ++m2)
        #pragma unroll
        for (int nt = 0; nt < 17; ++nt)
          #pragma unroll
          for (int e = 0; e < 4; ++e) acc[m2][nt][e] = 0.f;

      for (int kc = 0; kc < 2; ++kc) {
        __syncthreads();
        #pragma unroll 8
        for (int it = 0; it < 16; ++it) {
          const int li = it * 256 + tid;
          const int row = li >> 5;
          const int col = (li & 31) * 4;
          const float* sp = hsrc + (size_t)row * 256 + kc * 128 + col;
          union { u64 q; float f[2]; } a0, a1;
          a0.q = load_coh(sp);
          a1.q = load_coh(sp + 2);
          union { unsigned short s[4]; u64 q; } o;
          o.s[0] = f2bf(a0.f[0]); o.s[1] = f2bf(a0.f[1]);
          o.s[2] = f2bf(a1.f[0]); o.s[3] = f2bf(a1.f[1]);
          *(u64*)&Abuf[row * 136 + col] = o.q;
        }
        __syncthreads();
        // after kc==1 staging barrier all hbuf reads for this cell are done -> unblock writer
        // (barrier drained vmcnt, so relaxed post is safe)
        if (kc == 1 && tid == 0)
          __hip_atomic_fetch_add(&eflag[Le * 31 + r], 1, __ATOMIC_RELAXED, __HIP_MEMORY_SCOPE_AGENT);
        #pragma unroll
        for (int ks = 0; ks < 4; ++ks) {
          const int kofs = ks * 32 + quad * 8;
          s16x8 af[2];
          #pragma unroll
          for (int m2 = 0; m2 < 2; ++m2)
            af[m2] = *(const s16x8*)&Abuf[((wv * 2 + m2) * 16 + l16) * 136 + kofs];
          #pragma unroll
          for (int nt = 0; nt < 17; ++nt) {
            const s16x8 bf = *(const s16x8*)(W3c + (size_t)(nt * 16 + l16) * 256 + kc * 128 + kofs);
            #pragma unroll
            for (int m2 = 0; m2 < 2; ++m2)
              acc[m2][nt] = __builtin_amdgcn_mfma_f32_16x16x32_bf16(af[m2], bf, acc[m2][nt], 0, 0, 0);
          }
        }
      }

      const float* bias = (c == 0) ? red_b : (c == 1) ? green_b : blue_b;
      #pragma unroll
      for (int m2 = 0; m2 < 2; ++m2)
        #pragma unroll
        for (int i = 0; i < 4; ++i) {
          const int b = (m2 + wv * 2) * 16 + quad * 4 + i;
          const int t0 = idx0[b], t1 = idx1[b];
          float* orow = out + ((size_t)((b * 3 + c) * 31 + r) * 31 + k) * 257;
          #pragma unroll
          for (int nt = 0; nt < 17; ++nt) {
            const int v = nt * 16 + l16;
            if (v < 257) {
              float val = acc[m2][nt][i] + bias[v];
              if (c == 1)      val += TG[(size_t)t0 * 257 + v];
              else if (c == 2) val += TB0[(size_t)t0 * 257 + v] + TB1[(size_t)t1 * 257 + v];
              orow[v] = val;
            }
          }
        }
    }
  }
}

// ---------------- host launch ----------------

extern "C" void kernel_launch(void* const* d_in, const int* in_sizes, int n_in,
                              void* d_out, int out_size, void* d_ws, size_t ws_size,
                              hipStream_t stream) {
  const int*   x       = (const int*)  d_in[0];
  const float* emb     = (const float*)d_in[1];
  const float* xcomb_W = (const float*)d_in[2];
  const float* xcomb_b = (const float*)d_in[3];
  const float* hcomb_W = (const float*)d_in[4];
  const float* hcomb_b = (const float*)d_in[5];
  const float* W_ih    = (const float*)d_in[6];
  const float* W_hh    = (const float*)d_in[7];
  const float* b_ih    = (const float*)d_in[8];
  const float* b_hh    = (const float*)d_in[9];
  const float* red_W   = (const float*)d_in[10];
  const float* red_b   = (const float*)d_in[11];
  const float* green_W = (const float*)d_in[12];
  const float* green_b = (const float*)d_in[13];
  const float* blue_W  = (const float*)d_in[14];
  const float* blue_b  = (const float*)d_in[15];
  float* out = (float*)d_out;

  char* p = (char*)d_ws;
  auto alloc = [&](size_t bytes) -> char* {
    char* r = p; p += (bytes + 255) & ~(size_t)255; return r;
  };
  float* hbuf          = (float*)alloc((size_t)31 * 3 * 128 * 256 * 4);
  unsigned short* Wbig = (unsigned short*)alloc((size_t)3 * 1024 * 512 * 2);
  float* bbig          = (float*)alloc((size_t)3 * 1024 * 4);
  float* Tl            = (float*)alloc((size_t)3 * 257 * 768 * 4);
  float* Ta            = (float*)alloc((size_t)3 * 257 * 768 * 4);
  float* Ul            = (float*)alloc((size_t)3 * 257 * 256 * 4);
  float* Ua            = (float*)alloc((size_t)3 * 257 * 256 * 4);
  float* bgx           = (float*)alloc((size_t)3 * 768 * 4);
  unsigned short* W3   = (unsigned short*)alloc((size_t)3 * 272 * 256 * 2);
  float* TG            = (float*)alloc((size_t)257 * 257 * 4);
  float* TB0           = (float*)alloc((size_t)257 * 257 * 4);
  float* TB1           = (float*)alloc((size_t)257 * 257 * 4);
  int*   flags         = (int*)  alloc((size_t)2 * 124 * 31 * 4);
  float* pregx         = (float*)alloc((size_t)2883 * 3 * 128 * 256 * 4);  // 1.13 GB

  prep_wbig<<<dim3(3, 1024), dim3(256), 0, stream>>>(hcomb_W, hcomb_b, W_hh, b_hh, Wbig, bbig);
  prep_u<<<dim3(3, 257, 2), dim3(256), 0, stream>>>(emb, xcomb_W, Ul, Ua);
  prep_t<<<dim3(3, 257, 2), dim3(768), 0, stream>>>(W_ih, Ul, Ua, Tl, Ta);
  prep_bgx<<<dim3(3), dim3(768), 0, stream>>>(W_ih, xcomb_b, b_ih, bgx);
  prep_tgb<<<dim3(257, 3), dim3(320), 0, stream>>>(emb, green_W, blue_W, TG, TB0, TB1);
  prep_w3<<<dim3(3, 272), dim3(256), 0, stream>>>(red_W, green_W, blue_W, W3);
  prep_gx<<<dim3(31, 31, 3), dim3(256), 0, stream>>>(x, Tl, Ta, bgx, bbig, W_ih, pregx);
  zero_flags<<<dim3(31), dim3(256), 0, stream>>>(flags, 2 * 124 * 31);

  // one persistent launch: 155 active blocks (31 rows x {4 step roles + 1 epi}) <= 256 CUs
  persist_kernel<<<dim3(160), dim3(256), 0, stream>>>(
      x, hbuf, Wbig, bbig, pregx, W3, TG, TB0, TB1, red_b, green_b, blue_b, out, flags);
}